// Round 1
// baseline (347.903 us; speedup 1.0000x reference)
//
#include <hip/hip_runtime.h>

typedef __attribute__((ext_vector_type(8))) _Float16 half8;
typedef __attribute__((ext_vector_type(4))) float floatx4;

#define AS1 __attribute__((address_space(1)))
#define AS3 __attribute__((address_space(3)))

__device__ __forceinline__ void async_load16(const void* g, void* l) {
  __builtin_amdgcn_global_load_lds((AS1 void*)(unsigned long long)g,
                                   (AS3 void*)(unsigned long long)l, 16, 0, 0);
}

// ---------------- GroupNorm stats: one block per (b, g); region is contiguous 16*2048 floats
__global__ __launch_bounds__(256) void gn_stats(const float* __restrict__ x,
                                                float* __restrict__ stats) {
  const int bg = blockIdx.x;
  const float4* p4 = (const float4*)(x + (long long)bg * 32768);
  const int t = threadIdx.x;
  float s = 0.f, ss = 0.f;
  for (int i = t; i < 8192; i += 256) {
    float4 v = p4[i];
    s += v.x + v.y + v.z + v.w;
    ss += v.x * v.x + v.y * v.y + v.z * v.z + v.w * v.w;
  }
#pragma unroll
  for (int off = 32; off; off >>= 1) { s += __shfl_down(s, off); ss += __shfl_down(ss, off); }
  __shared__ float rs[4], rss[4];
  if ((t & 63) == 0) { rs[t >> 6] = s; rss[t >> 6] = ss; }
  __syncthreads();
  if (t == 0) {
    s = rs[0] + rs[1] + rs[2] + rs[3];
    ss = rss[0] + rss[1] + rss[2] + rss[3];
    float mean = s * (1.f / 32768.f);
    float var = ss * (1.f / 32768.f) - mean * mean;
    stats[bg] = mean;
    stats[256 + bg] = rsqrtf(var + 1e-5f);
  }
}

// ---------------- normalize + transpose: x[b,c,l] fp32 -> ht[b,l,c] fp16
__global__ __launch_bounds__(256) void gn_apply(const float* __restrict__ x,
                                                const float* __restrict__ stats,
                                                const float* __restrict__ gsc,
                                                const float* __restrict__ gbi,
                                                _Float16* __restrict__ ht) {
  __shared__ float tile[64][65];
  const int b = blockIdx.z, c0 = blockIdx.y * 64, l0 = blockIdx.x * 64;
  const int t = threadIdx.x, tr = t >> 6, tc = t & 63;
  const float* xb = x + ((long long)b * 512 + c0) * 2048 + l0;
#pragma unroll
  for (int p = 0; p < 16; ++p) {
    int row = tr + p * 4;
    tile[row][tc] = xb[(long long)row * 2048 + tc];
  }
  __syncthreads();
  const int c = c0 + tc;
  const int bg = b * 32 + (c >> 4);
  const float mean = stats[bg], rstd = stats[256 + bg];
  const float sc = gsc[c] * rstd;
  const float off = gbi[c] - mean * sc;
  _Float16* hb = ht + ((long long)b * 2048 + l0) * 512 + c0;
#pragma unroll
  for (int p = 0; p < 16; ++p) {
    int l = tr + p * 4;
    hb[(long long)l * 512 + tc] = (_Float16)(tile[tc][l] * sc + off);
  }
}

// ---------------- cast 4 weight matrices fp32 -> fp16 (each 512x512 = 2^18 elems)
__global__ __launch_bounds__(256) void cast_w(const float* __restrict__ w0, const float* __restrict__ w1,
                                              const float* __restrict__ w2, const float* __restrict__ w3,
                                              _Float16* __restrict__ outw) {
  const long long i = (long long)blockIdx.x * 256 + threadIdx.x;
  const int m = (int)(i >> 18);
  const int r = (int)(i & 262143);
  const float* w = (m == 0) ? w0 : (m == 1) ? w1 : (m == 2) ? w2 : w3;
  outw[i] = (_Float16)w[r];
}

// ---------------- generic C[M,N] = alpha * A[M,K] * Bt[N,K]^T (+bias)(+residual)
// 128x128 tile, BK=32, 4 waves x (4x4) mfma_f32_16x16x32_f16, global_load_lds staging.
template <int BIAS_MODE /*0 none,1 over n,2 over m*/, int OUT_TYPE /*0 f32,1 f16*/, bool RESIDUAL>
__global__ __launch_bounds__(256) void gemm_bt(
    const _Float16* __restrict__ A, long long sA, int lda,
    const _Float16* __restrict__ Bt, long long sB, int ldb,
    void* __restrict__ Cv, long long sC, int ldc,
    const float* __restrict__ bias,
    const float* __restrict__ resid, long long sR,
    float alpha, int K) {
  __shared__ __align__(16) _Float16 lsa[128 * 32];
  __shared__ __align__(16) _Float16 lsb[128 * 32];
  const int tid = threadIdx.x;
  const int wave = tid >> 6, lane = tid & 63;
  const int m0 = blockIdx.y * 128, n0 = blockIdx.x * 128;
  const int bz = blockIdx.z;
  A += (long long)bz * sA;
  Bt += (long long)bz * sB;

  // staging assignment: wave0/1 -> A rows 0-63/64-127, wave2/3 -> Bt rows 0-63/64-127
  const bool isA = (wave < 2);
  const _Float16* gsrc = isA ? A : Bt;
  const int ld = isA ? lda : ldb;
  const int rbase = (wave & 1) * 64;
  const int t0 = isA ? m0 : n0;
  _Float16* lbase = (isA ? lsa : lsb) + rbase * 32;
  const int grow = t0 + rbase + (lane >> 2);
  const int gcol = (lane & 3) * 8;

  floatx4 acc[4][4] = {};
  const int mw = (wave >> 1) * 64, nw = (wave & 1) * 64;
  const int fm = lane & 15;
  const int fr = (lane >> 4) * 8;

  for (int k0 = 0; k0 < K; k0 += 32) {
    __syncthreads();  // previous fragments consumed before overwrite
    const _Float16* g = gsrc + (long long)grow * ld + k0 + gcol;
#pragma unroll
    for (int s = 0; s < 4; ++s)
      async_load16(g + (long long)s * 16 * ld, lbase + s * 16 * 32);
    __syncthreads();  // drains vmcnt -> LDS visible
    half8 af[4], bfr[4];
#pragma unroll
    for (int i = 0; i < 4; ++i) af[i] = *(const half8*)&lsa[(mw + 16 * i + fm) * 32 + fr];
#pragma unroll
    for (int j = 0; j < 4; ++j) bfr[j] = *(const half8*)&lsb[(nw + 16 * j + fm) * 32 + fr];
#pragma unroll
    for (int i = 0; i < 4; ++i)
#pragma unroll
      for (int j = 0; j < 4; ++j)
        acc[i][j] = __builtin_amdgcn_mfma_f32_16x16x32_f16(af[i], bfr[j], acc[i][j], 0, 0, 0);
  }

  // epilogue: C/D layout col=lane&15, row=(lane>>4)*4+reg  [verified m89/m91]
  const int r0 = m0 + mw + (lane >> 4) * 4;
  const int c0 = n0 + nw + fm;
#pragma unroll
  for (int i = 0; i < 4; ++i) {
#pragma unroll
    for (int j = 0; j < 4; ++j) {
      const int cc = c0 + 16 * j;
#pragma unroll
      for (int t = 0; t < 4; ++t) {
        const int rr = r0 + 16 * i + t;
        float v = acc[i][j][t] * alpha;
        if (BIAS_MODE == 1) v += bias[cc];
        if (BIAS_MODE == 2) v += bias[rr];
        if (RESIDUAL) v += resid[(long long)bz * sR + (long long)rr * ldc + cc];
        const long long off = (long long)bz * sC + (long long)rr * ldc + cc;
        if (OUT_TYPE == 0) ((float*)Cv)[off] = v;
        else ((_Float16*)Cv)[off] = (_Float16)v;
      }
    }
  }
}

// ---------------- row softmax on S (fp16, in place). One block per row of 2048.
__global__ __launch_bounds__(256) void softmax_inplace(_Float16* __restrict__ S) {
  const long long row = (long long)blockIdx.y * 2048 + blockIdx.x;
  _Float16* p = S + row * 2048;
  const int t = threadIdx.x;
  union U { float4 f; _Float16 h[8]; } u;
  u.f = ((const float4*)p)[t];  // all reads complete before first barrier
  float v[8];
  float mx = -3e38f;
#pragma unroll
  for (int i = 0; i < 8; ++i) { v[i] = (float)u.h[i]; mx = fmaxf(mx, v[i]); }
#pragma unroll
  for (int off = 32; off; off >>= 1) mx = fmaxf(mx, __shfl_down(mx, off));
  __shared__ float red[4];
  if ((t & 63) == 0) red[t >> 6] = mx;
  __syncthreads();
  mx = fmaxf(fmaxf(red[0], red[1]), fmaxf(red[2], red[3]));
  float s = 0.f;
#pragma unroll
  for (int i = 0; i < 8; ++i) { v[i] = __expf(v[i] - mx); s += v[i]; }
#pragma unroll
  for (int off = 32; off; off >>= 1) s += __shfl_down(s, off);
  __syncthreads();
  if ((t & 63) == 0) red[t >> 6] = s;
  __syncthreads();
  s = red[0] + red[1] + red[2] + red[3];
  const float inv = 1.f / s;
#pragma unroll
  for (int i = 0; i < 8; ++i) u.h[i] = (_Float16)(v[i] * inv);
  ((float4*)p)[t] = u.f;  // writes only after final barrier
}

extern "C" void kernel_launch(void* const* d_in, const int* in_sizes, int n_in,
                              void* d_out, int out_size, void* d_ws, size_t ws_size,
                              hipStream_t stream) {
  const float* x = (const float*)d_in[0];
  const float* gsc = (const float*)d_in[1];
  const float* gbi = (const float*)d_in[2];
  const float* wq = (const float*)d_in[3];
  const float* bq = (const float*)d_in[4];
  const float* wk = (const float*)d_in[5];
  const float* bk = (const float*)d_in[6];
  const float* wv = (const float*)d_in[7];
  const float* bv = (const float*)d_in[8];
  const float* wo = (const float*)d_in[9];
  const float* bo = (const float*)d_in[10];
  float* out = (float*)d_out;

  // workspace layout (~130 MB total)
  char* ws = (char*)d_ws;
  float* stats = (float*)ws;                               // 512 f32
  _Float16* wbf = (_Float16*)(ws + 4096);                  // 4 * 512*512 f16
  _Float16* ht = (_Float16*)(ws + 4096 + 4 * 262144 * 2);  // [b,l,c] f16
  const long long EB = 8LL * 2048 * 512;
  _Float16* qt = ht + EB;   // [b,l,c]
  _Float16* kt = qt + EB;   // [b,l,c]
  _Float16* vm = kt + EB;   // [b,c,l]
  _Float16* Sb = vm + EB;   // [b,l,l] f16 (softmax in place)
  _Float16* at = ht;        // attention output aliases ht (ht dead after V-proj)

  gn_stats<<<256, 256, 0, stream>>>(x, stats);
  gn_apply<<<dim3(32, 8, 8), 256, 0, stream>>>(x, stats, gsc, gbi, ht);
  cast_w<<<4096, 256, 0, stream>>>(wq, wk, wv, wo, wbf);

  const float scale = 0.044194173824159216f;  // 512^-0.5
  // Q/K: [l,o] = ht[l,c] . W[o,c]^T + b[o]
  gemm_bt<1, 1, false><<<dim3(4, 16, 8), 256, 0, stream>>>(
      ht, 1048576LL, 512, wbf, 0LL, 512, qt, 1048576LL, 512, bq, nullptr, 0LL, 1.f, 512);
  gemm_bt<1, 1, false><<<dim3(4, 16, 8), 256, 0, stream>>>(
      ht, 1048576LL, 512, wbf + 262144, 0LL, 512, kt, 1048576LL, 512, bk, nullptr, 0LL, 1.f, 512);
  // V: [o,l] = Wv[o,c] . ht[l,c]^T + bv[o]
  gemm_bt<2, 1, false><<<dim3(16, 4, 8), 256, 0, stream>>>(
      wbf + 2 * 262144, 0LL, 512, ht, 1048576LL, 512, vm, 1048576LL, 2048, bv, nullptr, 0LL, 1.f, 512);
  // S: [i,j] = scale * q[i,o] . k[j,o]^T
  gemm_bt<0, 1, false><<<dim3(16, 16, 8), 256, 0, stream>>>(
      qt, 1048576LL, 512, kt, 1048576LL, 512, Sb, 4194304LL, 2048, nullptr, nullptr, 0LL, scale, 512);
  softmax_inplace<<<dim3(2048, 8), 256, 0, stream>>>(Sb);
  // A: [i,c] = P[i,j] . vm[c,j]^T
  gemm_bt<0, 1, false><<<dim3(4, 16, 8), 256, 0, stream>>>(
      Sb, 4194304LL, 2048, vm, 1048576LL, 2048, at, 1048576LL, 512, nullptr, nullptr, 0LL, 1.f, 2048);
  // Out: [o,l] = Wo[o,c] . a[l,c]^T + bo[o] + x[b,o,l]
  gemm_bt<2, 0, true><<<dim3(16, 4, 8), 256, 0, stream>>>(
      wbf + 3 * 262144, 0LL, 512, at, 1048576LL, 512, out, 1048576LL, 2048, bo, x, 1048576LL, 1.f, 512);
}

// Round 2
// 301.878 us; speedup vs baseline: 1.1525x; 1.1525x over previous
//
#include <hip/hip_runtime.h>

typedef __attribute__((ext_vector_type(8))) _Float16 half8;
typedef __attribute__((ext_vector_type(4))) float floatx4;

#define AS1 __attribute__((address_space(1)))
#define AS3 __attribute__((address_space(3)))

__device__ __forceinline__ void async_load16(const void* g, void* l) {
  __builtin_amdgcn_global_load_lds((AS1 void*)(unsigned long long)g,
                                   (AS3 void*)(unsigned long long)l, 16, 0, 0);
}

// ---------------- GroupNorm stats: one block per (b, g); region is contiguous 16*2048 floats
__global__ __launch_bounds__(256) void gn_stats(const float* __restrict__ x,
                                                float* __restrict__ stats) {
  const int bg = blockIdx.x;
  const float4* p4 = (const float4*)(x + (long long)bg * 32768);
  const int t = threadIdx.x;
  float s = 0.f, ss = 0.f;
  for (int i = t; i < 8192; i += 256) {
    float4 v = p4[i];
    s += v.x + v.y + v.z + v.w;
    ss += v.x * v.x + v.y * v.y + v.z * v.z + v.w * v.w;
  }
#pragma unroll
  for (int off = 32; off; off >>= 1) { s += __shfl_down(s, off); ss += __shfl_down(ss, off); }
  __shared__ float rs[4], rss[4];
  if ((t & 63) == 0) { rs[t >> 6] = s; rss[t >> 6] = ss; }
  __syncthreads();
  if (t == 0) {
    s = rs[0] + rs[1] + rs[2] + rs[3];
    ss = rss[0] + rss[1] + rss[2] + rss[3];
    float mean = s * (1.f / 32768.f);
    float var = ss * (1.f / 32768.f) - mean * mean;
    stats[bg] = mean;
    stats[256 + bg] = rsqrtf(var + 1e-5f);
  }
}

// ---------------- normalize + transpose: x[b,c,l] fp32 -> ht[b,l,c] fp16
__global__ __launch_bounds__(256) void gn_apply(const float* __restrict__ x,
                                                const float* __restrict__ stats,
                                                const float* __restrict__ gsc,
                                                const float* __restrict__ gbi,
                                                _Float16* __restrict__ ht) {
  __shared__ float tile[64][65];
  const int b = blockIdx.z, c0 = blockIdx.y * 64, l0 = blockIdx.x * 64;
  const int t = threadIdx.x, tr = t >> 6, tc = t & 63;
  const float* xb = x + ((long long)b * 512 + c0) * 2048 + l0;
#pragma unroll
  for (int p = 0; p < 16; ++p) {
    int row = tr + p * 4;
    tile[row][tc] = xb[(long long)row * 2048 + tc];
  }
  __syncthreads();
  const int c = c0 + tc;
  const int bg = b * 32 + (c >> 4);
  const float mean = stats[bg], rstd = stats[256 + bg];
  const float sc = gsc[c] * rstd;
  const float off = gbi[c] - mean * sc;
  _Float16* hb = ht + ((long long)b * 2048 + l0) * 512 + c0;
#pragma unroll
  for (int p = 0; p < 16; ++p) {
    int l = tr + p * 4;
    hb[(long long)l * 512 + tc] = (_Float16)(tile[tc][l] * sc + off);
  }
}

// ---------------- cast 4 weight matrices fp32 -> fp16, plus pack bq||bk into bqk (f32)
__global__ __launch_bounds__(256) void cast_w(const float* __restrict__ w0, const float* __restrict__ w1,
                                              const float* __restrict__ w2, const float* __restrict__ w3,
                                              const float* __restrict__ bq, const float* __restrict__ bk,
                                              _Float16* __restrict__ outw, float* __restrict__ bqk) {
  const long long i = (long long)blockIdx.x * 256 + threadIdx.x;
  if (blockIdx.x < 4096) {
    const int m = (int)(i >> 18);
    const int r = (int)(i & 262143);
    const float* w = (m == 0) ? w0 : (m == 1) ? w1 : (m == 2) ? w2 : w3;
    outw[i] = (_Float16)w[r];
  } else {
    const int j = (int)(i - 4096LL * 256);  // 0..1023
    bqk[j] = (j < 512) ? bq[j] : bk[j - 512];
  }
}

// ---------------- generic C[M,N] = alpha * A[M,K] * Bt[N,K]^T (+bias)(+residual)
// 128x128 tile, BK=64, XOR-swizzled LDS (conflict-free ds_read_b128),
// 4 waves x (4x4) mfma_f32_16x16x32_f16, global_load_lds width-16 staging.
// Grid: x = batch (XCD-local), y = m-tile, z = n-tile.
template <int BIAS_MODE /*0 none,1 over n,2 over m*/, int OUT_TYPE /*0 f32,1 f16*/, bool RESIDUAL>
__global__ __launch_bounds__(256) void gemm_bt(
    const _Float16* __restrict__ A, long long sA, int lda,
    const _Float16* __restrict__ Bt, long long sB, int ldb,
    void* __restrict__ Cv, long long sC, int ldc,
    const float* __restrict__ bias,
    const float* __restrict__ resid, long long sR,
    float alpha, int K) {
  __shared__ __align__(16) _Float16 lsa[128 * 64];
  __shared__ __align__(16) _Float16 lsb[128 * 64];
  const int tid = threadIdx.x;
  const int wave = tid >> 6, lane = tid & 63;
  const int bz = blockIdx.x;  // batch -> XCD (linear_id % 8 == batch)
  const int m0 = blockIdx.y * 128, n0 = blockIdx.z * 128;
  A += (long long)bz * sA;
  Bt += (long long)bz * sB;

  // staging: wave0/1 -> A rows 0-63/64-127, wave2/3 -> Bt rows 0-63/64-127.
  // XOR swizzle: global 16B-chunk c of row r lands at LDS chunk c^(r&7);
  // implemented by swizzling the *global* column each lane fetches.
  const bool isA = (wave < 2);
  const _Float16* gsrc = isA ? A : Bt;
  const int ld = isA ? lda : ldb;
  const int rbase = (wave & 1) * 64;
  const int t0 = isA ? m0 : n0;
  _Float16* lbase = (isA ? lsa : lsb) + rbase * 64;
  const int grow = t0 + rbase + (lane >> 3);
  const int gcol = ((lane & 7) ^ ((lane >> 3) & 7)) * 8;

  floatx4 acc[4][4] = {};
  const int mw = (wave >> 1) * 64, nw = (wave & 1) * 64;
  const int fm = lane & 15;
  const int quad = lane >> 4;

  for (int k0 = 0; k0 < K; k0 += 64) {
    __syncthreads();  // previous fragments consumed before overwrite
    const _Float16* g = gsrc + (long long)grow * ld + k0 + gcol;
#pragma unroll
    for (int s = 0; s < 8; ++s)
      async_load16(g + (long long)s * 8 * ld, lbase + s * 512);
    __syncthreads();  // drains vmcnt -> LDS visible
#pragma unroll
    for (int kk = 0; kk < 2; ++kk) {
      const int ca = quad + 4 * kk;           // global chunk wanted
      const int cs = (ca ^ (fm & 7)) * 8;     // swizzled LDS offset (halves)
      half8 af[4], bfr[4];
#pragma unroll
      for (int i = 0; i < 4; ++i) af[i] = *(const half8*)&lsa[(mw + 16 * i + fm) * 64 + cs];
#pragma unroll
      for (int j = 0; j < 4; ++j) bfr[j] = *(const half8*)&lsb[(nw + 16 * j + fm) * 64 + cs];
#pragma unroll
      for (int i = 0; i < 4; ++i)
#pragma unroll
        for (int j = 0; j < 4; ++j)
          acc[i][j] = __builtin_amdgcn_mfma_f32_16x16x32_f16(af[i], bfr[j], acc[i][j], 0, 0, 0);
    }
  }

  // epilogue: C/D layout col=lane&15, row=(lane>>4)*4+reg  [verified m89/m91]
  const int r0 = m0 + mw + quad * 4;
  const int c0 = n0 + nw + fm;
#pragma unroll
  for (int i = 0; i < 4; ++i) {
#pragma unroll
    for (int j = 0; j < 4; ++j) {
      const int cc = c0 + 16 * j;
#pragma unroll
      for (int t = 0; t < 4; ++t) {
        const int rr = r0 + 16 * i + t;
        float v = acc[i][j][t] * alpha;
        if (BIAS_MODE == 1) v += bias[cc];
        if (BIAS_MODE == 2) v += bias[rr];
        if (RESIDUAL) v += resid[(long long)bz * sR + (long long)rr * ldc + cc];
        const long long off = (long long)bz * sC + (long long)rr * ldc + cc;
        if (OUT_TYPE == 0) ((float*)Cv)[off] = v;
        else ((_Float16*)Cv)[off] = (_Float16)v;
      }
    }
  }
}

// ---------------- row softmax on S (fp16, in place). One block per row of 2048.
__global__ __launch_bounds__(256) void softmax_inplace(_Float16* __restrict__ S) {
  const long long row = (long long)blockIdx.y * 2048 + blockIdx.x;
  _Float16* p = S + row * 2048;
  const int t = threadIdx.x;
  union U { float4 f; _Float16 h[8]; } u;
  u.f = ((const float4*)p)[t];  // all reads complete before first barrier
  float v[8];
  float mx = -3e38f;
#pragma unroll
  for (int i = 0; i < 8; ++i) { v[i] = (float)u.h[i]; mx = fmaxf(mx, v[i]); }
#pragma unroll
  for (int off = 32; off; off >>= 1) mx = fmaxf(mx, __shfl_down(mx, off));
  __shared__ float red[4];
  if ((t & 63) == 0) red[t >> 6] = mx;
  __syncthreads();
  mx = fmaxf(fmaxf(red[0], red[1]), fmaxf(red[2], red[3]));
  float s = 0.f;
#pragma unroll
  for (int i = 0; i < 8; ++i) { v[i] = __expf(v[i] - mx); s += v[i]; }
#pragma unroll
  for (int off = 32; off; off >>= 1) s += __shfl_down(s, off);
  __syncthreads();
  if ((t & 63) == 0) red[t >> 6] = s;
  __syncthreads();
  s = red[0] + red[1] + red[2] + red[3];
  const float inv = 1.f / s;
#pragma unroll
  for (int i = 0; i < 8; ++i) u.h[i] = (_Float16)(v[i] * inv);
  ((float4*)p)[t] = u.f;  // writes only after final barrier
}

extern "C" void kernel_launch(void* const* d_in, const int* in_sizes, int n_in,
                              void* d_out, int out_size, void* d_ws, size_t ws_size,
                              hipStream_t stream) {
  const float* x = (const float*)d_in[0];
  const float* gsc = (const float*)d_in[1];
  const float* gbi = (const float*)d_in[2];
  const float* wq = (const float*)d_in[3];
  const float* bq = (const float*)d_in[4];
  const float* wk = (const float*)d_in[5];
  const float* bk = (const float*)d_in[6];
  const float* wv = (const float*)d_in[7];
  const float* bv = (const float*)d_in[8];
  const float* wo = (const float*)d_in[9];
  const float* bo = (const float*)d_in[10];
  float* out = (float*)d_out;

  // workspace layout (~130 MB total)
  char* ws = (char*)d_ws;
  float* stats = (float*)ws;                 // 512 f32 @ 0
  float* bqk = (float*)(ws + 2048);          // 1024 f32 @ 2 KB
  _Float16* wbf = (_Float16*)(ws + 8192);    // 4 * 512*512 f16 (wq,wk,wv,wo stacked)
  _Float16* ht = wbf + 4 * 262144;           // [b,l,c] f16, 16 MB
  const long long EB = 8LL * 2048 * 512;
  _Float16* qk = ht + EB;       // [b,l,1024] f16 (q||k), 32 MB
  _Float16* vm = qk + 2 * EB;   // [b,c,l] f16, 16 MB
  _Float16* Sb = vm + EB;       // [b,l,l] f16, 64 MB (softmax in place)
  _Float16* at = ht;            // attention output aliases ht (ht dead after V-proj)

  gn_stats<<<256, 256, 0, stream>>>(x, stats);
  gn_apply<<<dim3(32, 8, 8), 256, 0, stream>>>(x, stats, gsc, gbi, ht);
  cast_w<<<4100, 256, 0, stream>>>(wq, wk, wv, wo, bq, bk, wbf, bqk);

  const float scale = 0.044194173824159216f;  // 512^-0.5
  // QK fused: [l, 0:1024] = ht[l,c] . (wq||wk)[o,c]^T + bqk[o]
  gemm_bt<1, 1, false><<<dim3(8, 16, 8), 256, 0, stream>>>(
      ht, 1048576LL, 512, wbf, 0LL, 512, qk, 2097152LL, 1024, bqk, nullptr, 0LL, 1.f, 512);
  // V: [o,l] = Wv[o,c] . ht[l,c]^T + bv[o]
  gemm_bt<2, 1, false><<<dim3(8, 4, 16), 256, 0, stream>>>(
      wbf + 2 * 262144, 0LL, 512, ht, 1048576LL, 512, vm, 1048576LL, 2048, bv, nullptr, 0LL, 1.f, 512);
  // S: [i,j] = scale * q[i,o] . k[j,o]^T
  gemm_bt<0, 1, false><<<dim3(8, 16, 16), 256, 0, stream>>>(
      qk, 2097152LL, 1024, qk + 512, 2097152LL, 1024, Sb, 4194304LL, 2048, nullptr, nullptr, 0LL, scale, 512);
  softmax_inplace<<<dim3(2048, 8), 256, 0, stream>>>(Sb);
  // A: [i,c] = P[i,j] . vm[c,j]^T
  gemm_bt<0, 1, false><<<dim3(8, 16, 4), 256, 0, stream>>>(
      Sb, 4194304LL, 2048, vm, 1048576LL, 2048, at, 1048576LL, 512, nullptr, nullptr, 0LL, 1.f, 2048);
  // Out: [o,l] = Wo[o,c] . a[l,c]^T + bo[o] + x[b,o,l]
  gemm_bt<2, 0, true><<<dim3(8, 4, 16), 256, 0, stream>>>(
      wbf + 3 * 262144, 0LL, 512, at, 1048576LL, 512, out, 1048576LL, 2048, bo, x, 1048576LL, 1.f, 512);
}